// Round 6
// baseline (157.777 us; speedup 1.0000x reference)
//
#include <hip/hip_runtime.h>
#include <math.h>

#define C_NUM 80
#define T_NUM 256
#define EPSF  1e-7f
#define NBLK  2112              // 1600 (s0) + 400 (s1) + 112 (s2, 7/image)
#define PBLK_OFF 64

__device__ __forceinline__ float softplusf(float z) {
    return fmaxf(z, 0.0f) + log1pf(expf(-fabsf(z)));
}

// One block = 64 anchor slots of ONE (scale, image). 2112 blocks.
// Wave w owns classes [20w,20w+20); lane=(cq,ag): cq=lane>>4 -> 5-class strip,
// ag=lane&15 -> float4 anchor group a0+4ag. Wave 0 additionally runs the
// match phase (1 anchor/lane) overlapped with the class stream.
__global__ __launch_bounds__(256)
void yolo_fused(const float* __restrict__ cls0, const float* __restrict__ cls1,
                const float* __restrict__ cls2,
                const float* __restrict__ reg0, const float* __restrict__ reg1,
                const float* __restrict__ reg2,
                const float* __restrict__ tboxes, const int* __restrict__ t_batch,
                const int* __restrict__ t_cls,
                unsigned int* __restrict__ counter, float4* __restrict__ pblk,
                float* __restrict__ out)
{
    __shared__ float s_x1[T_NUM], s_y1[T_NUM], s_x2[T_NUM], s_y2[T_NUM], s_ar[T_NUM];
    __shared__ int   s_tc[T_NUM];
    __shared__ int   s_list[T_NUM];
    __shared__ int   s_wcnt[4];
    __shared__ float4 s_wmax[4][16];    // [wave][ag]: 20-class max of 4 anchors
    __shared__ int   s_btc[64] __attribute__((aligned(16)));
    __shared__ float s_red[4][4];
    __shared__ int   s_last;

    const int tid = threadIdx.x;
    const int bid = blockIdx.x;
    const int lane = tid & 63, wave = tid >> 6;
    const int cq = lane >> 4, ag = lane & 15;

    int s, b, a0, A, H; float stride;
    const float *clsp, *regp;
    if (bid < 1600)      { s = 0; b = bid / 100;            a0 = (bid % 100) * 64; A = 6400; H = 80; stride =  8.f; clsp = cls0; regp = reg0; }
    else if (bid < 2000) { int r = bid - 1600; s = 1; b = r / 25; a0 = (r % 25) * 64; A = 1600; H = 40; stride = 16.f; clsp = cls1; regp = reg1; }
    else                 { int r = bid - 2000; s = 2; b = r / 7;  a0 = (r % 7)  * 64; A = 400;  H = 20; stride = 32.f; clsp = cls2; regp = reg2; }

    // ---- stage targets + per-image order-preserving compaction ----
    {
        float4 t4 = reinterpret_cast<const float4*>(tboxes)[tid];
        s_x1[tid] = t4.x; s_y1[tid] = t4.y; s_x2[tid] = t4.z; s_y2[tid] = t4.w;
        s_ar[tid] = (t4.z - t4.x) * (t4.w - t4.y);
        s_tc[tid] = t_cls[tid];
    }
    int match = (t_batch[tid] == b) ? 1 : 0;
    unsigned long long mask = __ballot(match != 0);
    if (lane == 0) s_wcnt[wave] = __popcll(mask);
    __syncthreads();
    int base = 0;
    #pragma unroll
    for (int w = 0; w < 4; ++w) if (w < wave) base += s_wcnt[w];
    const int nT = s_wcnt[0] + s_wcnt[1] + s_wcnt[2] + s_wcnt[3];
    if (match) {
        int pfx = __popcll(mask & (((unsigned long long)1 << lane) - 1ull));
        s_list[base + pfx] = tid;       // ascending -> first-max tie kept
    }
    __syncthreads();

    // ---- wave 0: issue reg loads FIRST (vmcnt retires in order) ----
    const int am = a0 + lane;
    const bool amv = am < A;
    float rx = 0.f, ry = 0.f, rw = 0.f, rh = 0.f;
    {
        const float* rp = regp + (size_t)(b * 4) * (size_t)A + (amv ? am : 0);
        if (wave == 0) { rx = rp[0]; ry = rp[A]; rw = rp[2 * (size_t)A]; rh = rp[3 * (size_t)A]; }
    }

    // ---- all waves: 5 independent float4 class loads (the 43MB stream) ----
    const int cbase = wave * 20 + cq * 5;
    const int ga = a0 + 4 * ag;
    const float* p = clsp + ((size_t)(b * C_NUM + cbase)) * (size_t)A + ((ga < A) ? ga : a0);
    float4 z0 = *reinterpret_cast<const float4*>(p);
    float4 z1 = *reinterpret_cast<const float4*>(p + (size_t)A);
    float4 z2 = *reinterpret_cast<const float4*>(p + 2 * (size_t)A);
    float4 z3 = *reinterpret_cast<const float4*>(p + 3 * (size_t)A);
    float4 z4 = *reinterpret_cast<const float4*>(p + 4 * (size_t)A);

    // ---- wave 0: match phase (overlaps the in-flight class stream) ----
    float cnt = 0.f, boxs = 0.f;
    if (wave == 0) {
        if (amv) {
            float gx = (float)(am % H), gy = (float)(am / H);
            float x = (1.f / (1.f + expf(-rx)) + gx) * stride;
            float y = (1.f / (1.f + expf(-ry)) + gy) * stride;
            float w = expf(rw) * stride;
            float h = expf(rh) * stride;
            float px1 = x - 0.5f * w, py1 = y - 0.5f * h;
            float px2 = x + 0.5f * w, py2 = y + 0.5f * h;
            float pw = px2 - px1, ph = py2 - py1;
            float parea = pw * ph;

            float maxiou = -1.f; int best = 0;
            for (int j = 0; j < nT; ++j) {
                int t = s_list[j];
                float ix = fminf(px2, s_x2[t]) - fmaxf(px1, s_x1[t]);
                float iy = fminf(py2, s_y2[t]) - fmaxf(py1, s_y1[t]);
                float inter = fmaxf(ix, 0.f) * fmaxf(iy, 0.f);
                float iou = inter / (parea + s_ar[t] - inter + EPSF);
                if (iou > maxiou) { maxiou = iou; best = t; }
            }
            const bool pos = maxiou > 0.5f;
            s_btc[lane] = pos ? s_tc[best] : -1;

            if (pos) {
                cnt = 1.f;
                float gx1 = s_x1[best], gy1 = s_y1[best], gx2 = s_x2[best], gy2 = s_y2[best];
                float gw = gx2 - gx1, gh = gy2 - gy1;
                float ix = fminf(px2, gx2) - fmaxf(px1, gx1);
                float iy = fminf(py2, gy2) - fmaxf(py1, gy1);
                float inter = fmaxf(ix, 0.f) * fmaxf(iy, 0.f);
                float uni = parea + gw * gh - inter + EPSF;
                float iou = inter / uni;
                float cw = fmaxf(px2, gx2) - fminf(px1, gx1);
                float ch = fmaxf(py2, gy2) - fminf(py1, gy1);
                float c2 = cw * cw + ch * ch + EPSF;
                float dx = 0.5f * ((px1 + px2) - (gx1 + gx2));
                float dy = 0.5f * ((py1 + py2) - (gy1 + gy2));
                float rho2 = dx * dx + dy * dy;
                float dv = atanf(gw / (gh + EPSF)) - atanf(pw / (ph + EPSF));
                float v = 0.40528473456935108577f * dv * dv;   // (4/pi^2) dv^2
                float alpha = v / (v - iou + 1.f + EPSF);
                boxs = 1.f - (iou - rho2 / c2 - alpha * v);
            }
        } else {
            s_btc[lane] = -1;
        }
    }

    // ---- class max: 5-way in-register, then across cq strips ----
    float4 mx;
    mx.x = fmaxf(fmaxf(fmaxf(z0.x, z1.x), fmaxf(z2.x, z3.x)), z4.x);
    mx.y = fmaxf(fmaxf(fmaxf(z0.y, z1.y), fmaxf(z2.y, z3.y)), z4.y);
    mx.z = fmaxf(fmaxf(fmaxf(z0.z, z1.z), fmaxf(z2.z, z3.z)), z4.z);
    mx.w = fmaxf(fmaxf(fmaxf(z0.w, z1.w), fmaxf(z2.w, z3.w)), z4.w);
    #pragma unroll
    for (int d = 16; d <= 32; d <<= 1) {
        mx.x = fmaxf(mx.x, __shfl_xor(mx.x, d, 64));
        mx.y = fmaxf(mx.y, __shfl_xor(mx.y, d, 64));
        mx.z = fmaxf(mx.z, __shfl_xor(mx.z, d, 64));
        mx.w = fmaxf(mx.w, __shfl_xor(mx.w, d, 64));
    }
    if (cq == 0) s_wmax[wave][ag] = mx;
    __syncthreads();   // publishes s_wmax and wave 0's s_btc

    // ---- cls-BCE on live registers (pos anchors only) ----
    float clss = 0.f;
    {
        int4 t4 = *reinterpret_cast<const int4*>(&s_btc[4 * ag]);
        if ((t4.x >= 0) | (t4.y >= 0) | (t4.z >= 0) | (t4.w >= 0)) {
            const float4 zz[5] = { z0, z1, z2, z3, z4 };
            #pragma unroll
            for (int k = 0; k < 5; ++k) {
                const int cg = cbase + k;
                if (t4.x >= 0) { clss += softplusf(zz[k].x); if (cg == t4.x) clss -= zz[k].x; }
                if (t4.y >= 0) { clss += softplusf(zz[k].y); if (cg == t4.y) clss -= zz[k].y; }
                if (t4.z >= 0) { clss += softplusf(zz[k].z); if (cg == t4.z) clss -= zz[k].z; }
                if (t4.w >= 0) { clss += softplusf(zz[k].w); if (cg == t4.w) clss -= zz[k].w; }
            }
        }
    }

    // ---- obj (wave 0, one slot per lane) ----
    float objs = 0.f;
    if (wave == 0 && amv) {
        float m = -INFINITY;
        #pragma unroll
        for (int w = 0; w < 4; ++w)
            m = fmaxf(m, reinterpret_cast<const float*>(&s_wmax[w][lane >> 2])[lane & 3]);
        bool pos = s_btc[lane] >= 0;
        objs = softplusf(m) - (pos ? m : 0.f);
    }

    // ---- block reduction {npos, box, cls, obj} ----
    #pragma unroll
    for (int off = 32; off > 0; off >>= 1) {
        cnt  += __shfl_down(cnt,  off, 64);
        boxs += __shfl_down(boxs, off, 64);
        clss += __shfl_down(clss, off, 64);
        objs += __shfl_down(objs, off, 64);
    }
    if (lane == 0) {
        s_red[wave][0] = cnt;  s_red[wave][1] = boxs;
        s_red[wave][2] = clss; s_red[wave][3] = objs;
    }
    __syncthreads();
    if (tid == 0) {
        float4 v;
        v.x = s_red[0][0] + s_red[1][0] + s_red[2][0] + s_red[3][0];
        v.y = s_red[0][1] + s_red[1][1] + s_red[2][1] + s_red[3][1];
        v.z = s_red[0][2] + s_red[1][2] + s_red[2][2] + s_red[3][2];
        v.w = s_red[0][3] + s_red[1][3] + s_red[2][3] + s_red[3][3];
        pblk[bid] = v;
        __threadfence();
        unsigned int old = atomicAdd(counter, 1u);
        s_last = (old == NBLK - 1) ? 1 : 0;
    }
    __syncthreads();

    // ---- last block folds all 2112 partials ----
    if (s_last) {
        __threadfence();
        if (tid < 64) {
            float np0 = 0.f, np1 = 0.f, np2 = 0.f, bx0 = 0.f, bx1 = 0.f, bx2 = 0.f;
            float cl0 = 0.f, cl1 = 0.f, cl2 = 0.f, ob0 = 0.f, ob1 = 0.f, ob2 = 0.f;
            for (int i = tid; i < NBLK; i += 64) {
                float4 v = pblk[i];
                if (i < 1600)      { np0 += v.x; bx0 += v.y; cl0 += v.z; ob0 += v.w; }
                else if (i < 2000) { np1 += v.x; bx1 += v.y; cl1 += v.z; ob1 += v.w; }
                else               { np2 += v.x; bx2 += v.y; cl2 += v.z; ob2 += v.w; }
            }
            #pragma unroll
            for (int off = 32; off > 0; off >>= 1) {
                np0 += __shfl_down(np0, off, 64); np1 += __shfl_down(np1, off, 64);
                np2 += __shfl_down(np2, off, 64); bx0 += __shfl_down(bx0, off, 64);
                bx1 += __shfl_down(bx1, off, 64); bx2 += __shfl_down(bx2, off, 64);
                cl0 += __shfl_down(cl0, off, 64); cl1 += __shfl_down(cl1, off, 64);
                cl2 += __shfl_down(cl2, off, 64); ob0 += __shfl_down(ob0, off, 64);
                ob1 += __shfl_down(ob1, off, 64); ob2 += __shfl_down(ob2, off, 64);
            }
            if (tid == 0) {
                float np[3] = { fmaxf(np0, 1.f), fmaxf(np1, 1.f), fmaxf(np2, 1.f) };
                float bx[3] = { bx0, bx1, bx2 };
                float cl[3] = { cl0, cl1, cl2 };
                float ob[3] = { ob0, ob1, ob2 };
                const float inv_anch[3] = { 1.f / (16.f * 6400.f), 1.f / (16.f * 1600.f), 1.f / (16.f * 400.f) };
                float total = 0.f;
                #pragma unroll
                for (int k = 0; k < 3; ++k)
                    total += 7.5f * bx[k] / np[k]
                           + 0.5f * cl[k] / (np[k] * (float)C_NUM)
                           + ob[k] * inv_anch[k];
                out[0] = total;
            }
        }
    }
}

extern "C" void kernel_launch(void* const* d_in, const int* in_sizes, int n_in,
                              void* d_out, int out_size, void* d_ws, size_t ws_size,
                              hipStream_t stream) {
    const float *cls[3] = {nullptr, nullptr, nullptr};
    const float *reg[3] = {nullptr, nullptr, nullptr};
    const float *tboxes = nullptr;
    const int *t_batch = nullptr, *t_cls = nullptr;
    for (int i = 0; i < n_in; ++i) {
        switch (in_sizes[i]) {
            case 16 * 80 * 6400: cls[0] = (const float*)d_in[i]; break;
            case 16 * 80 * 1600: cls[1] = (const float*)d_in[i]; break;
            case 16 * 80 * 400:  cls[2] = (const float*)d_in[i]; break;
            case 16 * 4 * 6400:  reg[0] = (const float*)d_in[i]; break;
            case 16 * 4 * 1600:  reg[1] = (const float*)d_in[i]; break;
            case 16 * 4 * 400:   reg[2] = (const float*)d_in[i]; break;
            case 256 * 4:        tboxes = (const float*)d_in[i]; break;
            case 256:
                if (!t_batch) t_batch = (const int*)d_in[i];
                else          t_cls   = (const int*)d_in[i];
                break;
            default: break;
        }
    }
    unsigned int* counter = (unsigned int*)d_ws;
    float4*       pblk    = (float4*)((char*)d_ws + PBLK_OFF);
    float*        out     = (float*)d_out;

    hipMemsetAsync(counter, 0, sizeof(unsigned int), stream);
    hipLaunchKernelGGL(yolo_fused, dim3(NBLK), dim3(256), 0, stream,
                       cls[0], cls[1], cls[2], reg[0], reg[1], reg[2],
                       tboxes, t_batch, t_cls, counter, pblk, out);
}

// Round 7
// 153.729 us; speedup vs baseline: 1.0263x; 1.0263x over previous
//
#include <hip/hip_runtime.h>
#include <math.h>

#define C_NUM 80
#define T_NUM 256
#define EPSF  1e-7f
#define NBLK  2112              // 1600 (s0) + 400 (s1) + 112 (s2, 7/image)
#define NGRP  33                // completion tree: 33 groups x 64 blocks
// ws layout: [0..127] ctr2, [128 .. 128+33*128) ctr1[g] (one line each),
//            [8192 ..) 2112 float4 partials. memset zeroes [0, 4352).
#define CTR1_OFF  128
#define PBLK_OFF  8192
#define MEMSET_SZ (CTR1_OFF + NGRP * 128)

__device__ __forceinline__ float softplusf(float z) {
    return fmaxf(z, 0.0f) + log1pf(expf(-fabsf(z)));
}

// One block = 64 anchor slots of ONE (scale, image). 2112 blocks.
// Wave w owns classes [20w,20w+20); lane=(cq,ag): cq=lane>>4 -> 5-class strip,
// ag=lane&15 -> float4 anchor group a0+4ag. Wave 0 additionally runs the
// match phase (1 anchor/lane) overlapped with the class stream.
// Completion: per-group counter (64 blocks, own cache line) -> global counter
// (33 RMWs) -> final block reduces. Avoids 2112 serialized same-line atomics
// (~90 cyc each = the 80us wall seen in R6).
__global__ __launch_bounds__(256)
void yolo_fused(const float* __restrict__ cls0, const float* __restrict__ cls1,
                const float* __restrict__ cls2,
                const float* __restrict__ reg0, const float* __restrict__ reg1,
                const float* __restrict__ reg2,
                const float* __restrict__ tboxes, const int* __restrict__ t_batch,
                const int* __restrict__ t_cls,
                unsigned int* __restrict__ ctr2, unsigned int* __restrict__ ctr1,
                float4* __restrict__ pblk, float* __restrict__ out)
{
    __shared__ float s_x1[T_NUM], s_y1[T_NUM], s_x2[T_NUM], s_y2[T_NUM], s_ar[T_NUM];
    __shared__ int   s_tc[T_NUM];
    __shared__ int   s_list[T_NUM];
    __shared__ int   s_wcnt[4];
    __shared__ float4 s_wmax[4][16];    // [wave][ag]: 20-class max of 4 anchors
    __shared__ int   s_btc[64] __attribute__((aligned(16)));
    __shared__ float s_red[4][4];
    __shared__ int   s_gfin, s_final;

    const int tid = threadIdx.x;
    const int bid = blockIdx.x;
    const int lane = tid & 63, wave = tid >> 6;
    const int cq = lane >> 4, ag = lane & 15;

    int s, b, a0, A, H; float stride;
    const float *clsp, *regp;
    if (bid < 1600)      { s = 0; b = bid / 100;            a0 = (bid % 100) * 64; A = 6400; H = 80; stride =  8.f; clsp = cls0; regp = reg0; }
    else if (bid < 2000) { int r = bid - 1600; s = 1; b = r / 25; a0 = (r % 25) * 64; A = 1600; H = 40; stride = 16.f; clsp = cls1; regp = reg1; }
    else                 { int r = bid - 2000; s = 2; b = r / 7;  a0 = (r % 7)  * 64; A = 400;  H = 20; stride = 32.f; clsp = cls2; regp = reg2; }

    // ---- stage targets + per-image order-preserving compaction ----
    {
        float4 t4 = reinterpret_cast<const float4*>(tboxes)[tid];
        s_x1[tid] = t4.x; s_y1[tid] = t4.y; s_x2[tid] = t4.z; s_y2[tid] = t4.w;
        s_ar[tid] = (t4.z - t4.x) * (t4.w - t4.y);
        s_tc[tid] = t_cls[tid];
    }
    int match = (t_batch[tid] == b) ? 1 : 0;
    unsigned long long mask = __ballot(match != 0);
    if (lane == 0) s_wcnt[wave] = __popcll(mask);
    __syncthreads();
    int base = 0;
    #pragma unroll
    for (int w = 0; w < 4; ++w) if (w < wave) base += s_wcnt[w];
    const int nT = s_wcnt[0] + s_wcnt[1] + s_wcnt[2] + s_wcnt[3];
    if (match) {
        int pfx = __popcll(mask & (((unsigned long long)1 << lane) - 1ull));
        s_list[base + pfx] = tid;       // ascending -> first-max tie kept
    }
    __syncthreads();

    // ---- wave 0: issue reg loads FIRST (vmcnt retires in order) ----
    const int am = a0 + lane;
    const bool amv = am < A;
    float rx = 0.f, ry = 0.f, rw = 0.f, rh = 0.f;
    {
        const float* rp = regp + (size_t)(b * 4) * (size_t)A + (amv ? am : 0);
        if (wave == 0) { rx = rp[0]; ry = rp[A]; rw = rp[2 * (size_t)A]; rh = rp[3 * (size_t)A]; }
    }

    // ---- all waves: 5 independent float4 class loads (the 43MB stream) ----
    const int cbase = wave * 20 + cq * 5;
    const int ga = a0 + 4 * ag;
    const float* p = clsp + ((size_t)(b * C_NUM + cbase)) * (size_t)A + ((ga < A) ? ga : a0);
    float4 z0 = *reinterpret_cast<const float4*>(p);
    float4 z1 = *reinterpret_cast<const float4*>(p + (size_t)A);
    float4 z2 = *reinterpret_cast<const float4*>(p + 2 * (size_t)A);
    float4 z3 = *reinterpret_cast<const float4*>(p + 3 * (size_t)A);
    float4 z4 = *reinterpret_cast<const float4*>(p + 4 * (size_t)A);

    // ---- wave 0: match phase (overlaps the in-flight class stream) ----
    float cnt = 0.f, boxs = 0.f;
    if (wave == 0) {
        if (amv) {
            float gx = (float)(am % H), gy = (float)(am / H);
            float x = (1.f / (1.f + expf(-rx)) + gx) * stride;
            float y = (1.f / (1.f + expf(-ry)) + gy) * stride;
            float w = expf(rw) * stride;
            float h = expf(rh) * stride;
            float px1 = x - 0.5f * w, py1 = y - 0.5f * h;
            float px2 = x + 0.5f * w, py2 = y + 0.5f * h;
            float pw = px2 - px1, ph = py2 - py1;
            float parea = pw * ph;

            float maxiou = -1.f; int best = 0;
            for (int j = 0; j < nT; ++j) {
                int t = s_list[j];
                float ix = fminf(px2, s_x2[t]) - fmaxf(px1, s_x1[t]);
                float iy = fminf(py2, s_y2[t]) - fmaxf(py1, s_y1[t]);
                float inter = fmaxf(ix, 0.f) * fmaxf(iy, 0.f);
                float iou = inter / (parea + s_ar[t] - inter + EPSF);
                if (iou > maxiou) { maxiou = iou; best = t; }
            }
            const bool pos = maxiou > 0.5f;
            s_btc[lane] = pos ? s_tc[best] : -1;

            if (pos) {
                cnt = 1.f;
                float gx1 = s_x1[best], gy1 = s_y1[best], gx2 = s_x2[best], gy2 = s_y2[best];
                float gw = gx2 - gx1, gh = gy2 - gy1;
                float ix = fminf(px2, gx2) - fmaxf(px1, gx1);
                float iy = fminf(py2, gy2) - fmaxf(py1, gy1);
                float inter = fmaxf(ix, 0.f) * fmaxf(iy, 0.f);
                float uni = parea + gw * gh - inter + EPSF;
                float iou = inter / uni;
                float cw = fmaxf(px2, gx2) - fminf(px1, gx1);
                float ch = fmaxf(py2, gy2) - fminf(py1, gy1);
                float c2 = cw * cw + ch * ch + EPSF;
                float dx = 0.5f * ((px1 + px2) - (gx1 + gx2));
                float dy = 0.5f * ((py1 + py2) - (gy1 + gy2));
                float rho2 = dx * dx + dy * dy;
                float dv = atanf(gw / (gh + EPSF)) - atanf(pw / (ph + EPSF));
                float v = 0.40528473456935108577f * dv * dv;   // (4/pi^2) dv^2
                float alpha = v / (v - iou + 1.f + EPSF);
                boxs = 1.f - (iou - rho2 / c2 - alpha * v);
            }
        } else {
            s_btc[lane] = -1;
        }
    }

    // ---- class max: 5-way in-register, then across cq strips ----
    float4 mx;
    mx.x = fmaxf(fmaxf(fmaxf(z0.x, z1.x), fmaxf(z2.x, z3.x)), z4.x);
    mx.y = fmaxf(fmaxf(fmaxf(z0.y, z1.y), fmaxf(z2.y, z3.y)), z4.y);
    mx.z = fmaxf(fmaxf(fmaxf(z0.z, z1.z), fmaxf(z2.z, z3.z)), z4.z);
    mx.w = fmaxf(fmaxf(fmaxf(z0.w, z1.w), fmaxf(z2.w, z3.w)), z4.w);
    #pragma unroll
    for (int d = 16; d <= 32; d <<= 1) {
        mx.x = fmaxf(mx.x, __shfl_xor(mx.x, d, 64));
        mx.y = fmaxf(mx.y, __shfl_xor(mx.y, d, 64));
        mx.z = fmaxf(mx.z, __shfl_xor(mx.z, d, 64));
        mx.w = fmaxf(mx.w, __shfl_xor(mx.w, d, 64));
    }
    if (cq == 0) s_wmax[wave][ag] = mx;
    __syncthreads();   // publishes s_wmax and wave 0's s_btc

    // ---- cls-BCE on live registers (pos anchors only) ----
    float clss = 0.f;
    {
        int4 t4 = *reinterpret_cast<const int4*>(&s_btc[4 * ag]);
        if ((t4.x >= 0) | (t4.y >= 0) | (t4.z >= 0) | (t4.w >= 0)) {
            const float4 zz[5] = { z0, z1, z2, z3, z4 };
            #pragma unroll
            for (int k = 0; k < 5; ++k) {
                const int cg = cbase + k;
                if (t4.x >= 0) { clss += softplusf(zz[k].x); if (cg == t4.x) clss -= zz[k].x; }
                if (t4.y >= 0) { clss += softplusf(zz[k].y); if (cg == t4.y) clss -= zz[k].y; }
                if (t4.z >= 0) { clss += softplusf(zz[k].z); if (cg == t4.z) clss -= zz[k].z; }
                if (t4.w >= 0) { clss += softplusf(zz[k].w); if (cg == t4.w) clss -= zz[k].w; }
            }
        }
    }

    // ---- obj (wave 0, one slot per lane) ----
    float objs = 0.f;
    if (wave == 0 && amv) {
        float m = -INFINITY;
        #pragma unroll
        for (int w = 0; w < 4; ++w)
            m = fmaxf(m, reinterpret_cast<const float*>(&s_wmax[w][lane >> 2])[lane & 3]);
        bool pos = s_btc[lane] >= 0;
        objs = softplusf(m) - (pos ? m : 0.f);
    }

    // ---- block reduction {npos, box, cls, obj} ----
    #pragma unroll
    for (int off = 32; off > 0; off >>= 1) {
        cnt  += __shfl_down(cnt,  off, 64);
        boxs += __shfl_down(boxs, off, 64);
        clss += __shfl_down(clss, off, 64);
        objs += __shfl_down(objs, off, 64);
    }
    if (lane == 0) {
        s_red[wave][0] = cnt;  s_red[wave][1] = boxs;
        s_red[wave][2] = clss; s_red[wave][3] = objs;
    }
    __syncthreads();

    // ---- completion tree: group line (64 RMWs) -> global line (33 RMWs) ----
    if (tid == 0) {
        float4 v;
        v.x = s_red[0][0] + s_red[1][0] + s_red[2][0] + s_red[3][0];
        v.y = s_red[0][1] + s_red[1][1] + s_red[2][1] + s_red[3][1];
        v.z = s_red[0][2] + s_red[1][2] + s_red[2][2] + s_red[3][2];
        v.w = s_red[0][3] + s_red[1][3] + s_red[2][3] + s_red[3][3];
        pblk[bid] = v;
        __threadfence();                                   // release partials
        unsigned int o1 = atomicAdd(&ctr1[(bid >> 6) * 32], 1u);
        s_gfin = (o1 == 63u) ? 1 : 0;
    }
    __syncthreads();
    if (!s_gfin) return;                                   // non-finishers exit now

    if (tid == 0) {
        __threadfence();
        unsigned int o2 = atomicAdd(ctr2, 1u);
        s_final = (o2 == NGRP - 1) ? 1 : 0;
    }
    __syncthreads();
    if (!s_final) return;

    // ---- final block folds all 2112 partials ----
    __threadfence();                                       // acquire
    if (tid < 64) {
        float np0 = 0.f, np1 = 0.f, np2 = 0.f, bx0 = 0.f, bx1 = 0.f, bx2 = 0.f;
        float cl0 = 0.f, cl1 = 0.f, cl2 = 0.f, ob0 = 0.f, ob1 = 0.f, ob2 = 0.f;
        for (int i = tid; i < NBLK; i += 64) {
            float4 v = pblk[i];
            if (i < 1600)      { np0 += v.x; bx0 += v.y; cl0 += v.z; ob0 += v.w; }
            else if (i < 2000) { np1 += v.x; bx1 += v.y; cl1 += v.z; ob1 += v.w; }
            else               { np2 += v.x; bx2 += v.y; cl2 += v.z; ob2 += v.w; }
        }
        #pragma unroll
        for (int off = 32; off > 0; off >>= 1) {
            np0 += __shfl_down(np0, off, 64); np1 += __shfl_down(np1, off, 64);
            np2 += __shfl_down(np2, off, 64); bx0 += __shfl_down(bx0, off, 64);
            bx1 += __shfl_down(bx1, off, 64); bx2 += __shfl_down(bx2, off, 64);
            cl0 += __shfl_down(cl0, off, 64); cl1 += __shfl_down(cl1, off, 64);
            cl2 += __shfl_down(cl2, off, 64); ob0 += __shfl_down(ob0, off, 64);
            ob1 += __shfl_down(ob1, off, 64); ob2 += __shfl_down(ob2, off, 64);
        }
        if (tid == 0) {
            float np[3] = { fmaxf(np0, 1.f), fmaxf(np1, 1.f), fmaxf(np2, 1.f) };
            float bx[3] = { bx0, bx1, bx2 };
            float cl[3] = { cl0, cl1, cl2 };
            float ob[3] = { ob0, ob1, ob2 };
            const float inv_anch[3] = { 1.f / (16.f * 6400.f), 1.f / (16.f * 1600.f), 1.f / (16.f * 400.f) };
            float total = 0.f;
            #pragma unroll
            for (int k = 0; k < 3; ++k)
                total += 7.5f * bx[k] / np[k]
                       + 0.5f * cl[k] / (np[k] * (float)C_NUM)
                       + ob[k] * inv_anch[k];
            out[0] = total;
        }
    }
}

extern "C" void kernel_launch(void* const* d_in, const int* in_sizes, int n_in,
                              void* d_out, int out_size, void* d_ws, size_t ws_size,
                              hipStream_t stream) {
    const float *cls[3] = {nullptr, nullptr, nullptr};
    const float *reg[3] = {nullptr, nullptr, nullptr};
    const float *tboxes = nullptr;
    const int *t_batch = nullptr, *t_cls = nullptr;
    for (int i = 0; i < n_in; ++i) {
        switch (in_sizes[i]) {
            case 16 * 80 * 6400: cls[0] = (const float*)d_in[i]; break;
            case 16 * 80 * 1600: cls[1] = (const float*)d_in[i]; break;
            case 16 * 80 * 400:  cls[2] = (const float*)d_in[i]; break;
            case 16 * 4 * 6400:  reg[0] = (const float*)d_in[i]; break;
            case 16 * 4 * 1600:  reg[1] = (const float*)d_in[i]; break;
            case 16 * 4 * 400:   reg[2] = (const float*)d_in[i]; break;
            case 256 * 4:        tboxes = (const float*)d_in[i]; break;
            case 256:
                if (!t_batch) t_batch = (const int*)d_in[i];
                else          t_cls   = (const int*)d_in[i];
                break;
            default: break;
        }
    }
    unsigned int* ctr2 = (unsigned int*)d_ws;
    unsigned int* ctr1 = (unsigned int*)((char*)d_ws + CTR1_OFF);
    float4*       pblk = (float4*)((char*)d_ws + PBLK_OFF);
    float*        out  = (float*)d_out;

    hipMemsetAsync(d_ws, 0, MEMSET_SZ, stream);
    hipLaunchKernelGGL(yolo_fused, dim3(NBLK), dim3(256), 0, stream,
                       cls[0], cls[1], cls[2], reg[0], reg[1], reg[2],
                       tboxes, t_batch, t_cls, ctr2, ctr1, pblk, out);
}

// Round 8
// 106.834 us; speedup vs baseline: 1.4768x; 1.4389x over previous
//
#include <hip/hip_runtime.h>
#include <math.h>

#define C_NUM 80
#define T_NUM 256
#define EPSF  1e-7f
#define NBLK  2112              // 1600 (s0) + 400 (s1) + 112 (s2, 7/image)

__device__ __forceinline__ float softplusf(float z) {
    return fmaxf(z, 0.0f) + log1pf(expf(-fabsf(z)));
}

// One block = 64 anchor slots of ONE (scale, image). 2112 blocks.
// Wave w owns classes [20w,20w+20); lane=(cq,ag): cq=lane>>4 -> 5-class strip,
// ag=lane&15 -> float4 anchor group a0+4ag. Wave 0 additionally runs the
// match phase (1 anchor/lane) overlapped with the class stream.
// NO fences / NO completion counter: per-block partials are plain stores;
// a second kernel (launch boundary = the sync) folds them. R5-R7 showed
// __threadfence's per-block L2 writeback serializes at ~35-70ns/block
// (2112 blocks -> ~72us wall); the kernel boundary removes it entirely.
__global__ __launch_bounds__(256)
void yolo_main(const float* __restrict__ cls0, const float* __restrict__ cls1,
               const float* __restrict__ cls2,
               const float* __restrict__ reg0, const float* __restrict__ reg1,
               const float* __restrict__ reg2,
               const float* __restrict__ tboxes, const int* __restrict__ t_batch,
               const int* __restrict__ t_cls, float4* __restrict__ pblk)
{
    __shared__ float s_x1[T_NUM], s_y1[T_NUM], s_x2[T_NUM], s_y2[T_NUM], s_ar[T_NUM];
    __shared__ int   s_tc[T_NUM];
    __shared__ int   s_list[T_NUM];
    __shared__ int   s_wcnt[4];
    __shared__ float4 s_wmax[4][16];    // [wave][ag]: 20-class max of 4 anchors
    __shared__ int   s_btc[64] __attribute__((aligned(16)));
    __shared__ float s_red[4][4];

    const int tid = threadIdx.x;
    const int bid = blockIdx.x;
    const int lane = tid & 63, wave = tid >> 6;
    const int cq = lane >> 4, ag = lane & 15;

    int s, b, a0, A, H; float stride;
    const float *clsp, *regp;
    if (bid < 1600)      { s = 0; b = bid / 100;            a0 = (bid % 100) * 64; A = 6400; H = 80; stride =  8.f; clsp = cls0; regp = reg0; }
    else if (bid < 2000) { int r = bid - 1600; s = 1; b = r / 25; a0 = (r % 25) * 64; A = 1600; H = 40; stride = 16.f; clsp = cls1; regp = reg1; }
    else                 { int r = bid - 2000; s = 2; b = r / 7;  a0 = (r % 7)  * 64; A = 400;  H = 20; stride = 32.f; clsp = cls2; regp = reg2; }
    (void)s;

    // ---- stage targets + per-image order-preserving compaction ----
    {
        float4 t4 = reinterpret_cast<const float4*>(tboxes)[tid];
        s_x1[tid] = t4.x; s_y1[tid] = t4.y; s_x2[tid] = t4.z; s_y2[tid] = t4.w;
        s_ar[tid] = (t4.z - t4.x) * (t4.w - t4.y);
        s_tc[tid] = t_cls[tid];
    }
    int match = (t_batch[tid] == b) ? 1 : 0;
    unsigned long long mask = __ballot(match != 0);
    if (lane == 0) s_wcnt[wave] = __popcll(mask);
    __syncthreads();
    int base = 0;
    #pragma unroll
    for (int w = 0; w < 4; ++w) if (w < wave) base += s_wcnt[w];
    const int nT = s_wcnt[0] + s_wcnt[1] + s_wcnt[2] + s_wcnt[3];
    if (match) {
        int pfx = __popcll(mask & (((unsigned long long)1 << lane) - 1ull));
        s_list[base + pfx] = tid;       // ascending -> first-max tie kept
    }
    __syncthreads();

    // ---- wave 0: issue reg loads FIRST (vmcnt retires in order) ----
    const int am = a0 + lane;
    const bool amv = am < A;
    float rx = 0.f, ry = 0.f, rw = 0.f, rh = 0.f;
    {
        const float* rp = regp + (size_t)(b * 4) * (size_t)A + (amv ? am : 0);
        if (wave == 0) { rx = rp[0]; ry = rp[A]; rw = rp[2 * (size_t)A]; rh = rp[3 * (size_t)A]; }
    }

    // ---- all waves: 5 independent float4 class loads (the 43MB stream) ----
    const int cbase = wave * 20 + cq * 5;
    const int ga = a0 + 4 * ag;
    const float* p = clsp + ((size_t)(b * C_NUM + cbase)) * (size_t)A + ((ga < A) ? ga : a0);
    float4 z0 = *reinterpret_cast<const float4*>(p);
    float4 z1 = *reinterpret_cast<const float4*>(p + (size_t)A);
    float4 z2 = *reinterpret_cast<const float4*>(p + 2 * (size_t)A);
    float4 z3 = *reinterpret_cast<const float4*>(p + 3 * (size_t)A);
    float4 z4 = *reinterpret_cast<const float4*>(p + 4 * (size_t)A);

    // ---- wave 0: match phase (overlaps the in-flight class stream) ----
    float cnt = 0.f, boxs = 0.f;
    if (wave == 0) {
        if (amv) {
            float gx = (float)(am % H), gy = (float)(am / H);
            float x = (1.f / (1.f + expf(-rx)) + gx) * stride;
            float y = (1.f / (1.f + expf(-ry)) + gy) * stride;
            float w = expf(rw) * stride;
            float h = expf(rh) * stride;
            float px1 = x - 0.5f * w, py1 = y - 0.5f * h;
            float px2 = x + 0.5f * w, py2 = y + 0.5f * h;
            float pw = px2 - px1, ph = py2 - py1;
            float parea = pw * ph;

            float maxiou = -1.f; int best = 0;
            for (int j = 0; j < nT; ++j) {
                int t = s_list[j];
                float ix = fminf(px2, s_x2[t]) - fmaxf(px1, s_x1[t]);
                float iy = fminf(py2, s_y2[t]) - fmaxf(py1, s_y1[t]);
                float inter = fmaxf(ix, 0.f) * fmaxf(iy, 0.f);
                float iou = inter / (parea + s_ar[t] - inter + EPSF);
                if (iou > maxiou) { maxiou = iou; best = t; }
            }
            const bool pos = maxiou > 0.5f;
            s_btc[lane] = pos ? s_tc[best] : -1;

            if (pos) {
                cnt = 1.f;
                float gx1 = s_x1[best], gy1 = s_y1[best], gx2 = s_x2[best], gy2 = s_y2[best];
                float gw = gx2 - gx1, gh = gy2 - gy1;
                float ix = fminf(px2, gx2) - fmaxf(px1, gx1);
                float iy = fminf(py2, gy2) - fmaxf(py1, gy1);
                float inter = fmaxf(ix, 0.f) * fmaxf(iy, 0.f);
                float uni = parea + gw * gh - inter + EPSF;
                float iou = inter / uni;
                float cw = fmaxf(px2, gx2) - fminf(px1, gx1);
                float ch = fmaxf(py2, gy2) - fminf(py1, gy1);
                float c2 = cw * cw + ch * ch + EPSF;
                float dx = 0.5f * ((px1 + px2) - (gx1 + gx2));
                float dy = 0.5f * ((py1 + py2) - (gy1 + gy2));
                float rho2 = dx * dx + dy * dy;
                float dv = atanf(gw / (gh + EPSF)) - atanf(pw / (ph + EPSF));
                float v = 0.40528473456935108577f * dv * dv;   // (4/pi^2) dv^2
                float alpha = v / (v - iou + 1.f + EPSF);
                boxs = 1.f - (iou - rho2 / c2 - alpha * v);
            }
        } else {
            s_btc[lane] = -1;
        }
    }

    // ---- class max: 5-way in-register, then across cq strips ----
    float4 mx;
    mx.x = fmaxf(fmaxf(fmaxf(z0.x, z1.x), fmaxf(z2.x, z3.x)), z4.x);
    mx.y = fmaxf(fmaxf(fmaxf(z0.y, z1.y), fmaxf(z2.y, z3.y)), z4.y);
    mx.z = fmaxf(fmaxf(fmaxf(z0.z, z1.z), fmaxf(z2.z, z3.z)), z4.z);
    mx.w = fmaxf(fmaxf(fmaxf(z0.w, z1.w), fmaxf(z2.w, z3.w)), z4.w);
    #pragma unroll
    for (int d = 16; d <= 32; d <<= 1) {
        mx.x = fmaxf(mx.x, __shfl_xor(mx.x, d, 64));
        mx.y = fmaxf(mx.y, __shfl_xor(mx.y, d, 64));
        mx.z = fmaxf(mx.z, __shfl_xor(mx.z, d, 64));
        mx.w = fmaxf(mx.w, __shfl_xor(mx.w, d, 64));
    }
    if (cq == 0) s_wmax[wave][ag] = mx;
    __syncthreads();   // publishes s_wmax and wave 0's s_btc

    // ---- cls-BCE on live registers (pos anchors only) ----
    float clss = 0.f;
    {
        int4 t4 = *reinterpret_cast<const int4*>(&s_btc[4 * ag]);
        if ((t4.x >= 0) | (t4.y >= 0) | (t4.z >= 0) | (t4.w >= 0)) {
            const float4 zz[5] = { z0, z1, z2, z3, z4 };
            #pragma unroll
            for (int k = 0; k < 5; ++k) {
                const int cg = cbase + k;
                if (t4.x >= 0) { clss += softplusf(zz[k].x); if (cg == t4.x) clss -= zz[k].x; }
                if (t4.y >= 0) { clss += softplusf(zz[k].y); if (cg == t4.y) clss -= zz[k].y; }
                if (t4.z >= 0) { clss += softplusf(zz[k].z); if (cg == t4.z) clss -= zz[k].z; }
                if (t4.w >= 0) { clss += softplusf(zz[k].w); if (cg == t4.w) clss -= zz[k].w; }
            }
        }
    }

    // ---- obj (wave 0, one slot per lane) ----
    float objs = 0.f;
    if (wave == 0 && amv) {
        float m = -INFINITY;
        #pragma unroll
        for (int w = 0; w < 4; ++w)
            m = fmaxf(m, reinterpret_cast<const float*>(&s_wmax[w][lane >> 2])[lane & 3]);
        bool pos = s_btc[lane] >= 0;
        objs = softplusf(m) - (pos ? m : 0.f);
    }

    // ---- block reduction {npos, box, cls, obj} -> one plain float4 store ----
    #pragma unroll
    for (int off = 32; off > 0; off >>= 1) {
        cnt  += __shfl_down(cnt,  off, 64);
        boxs += __shfl_down(boxs, off, 64);
        clss += __shfl_down(clss, off, 64);
        objs += __shfl_down(objs, off, 64);
    }
    if (lane == 0) {
        s_red[wave][0] = cnt;  s_red[wave][1] = boxs;
        s_red[wave][2] = clss; s_red[wave][3] = objs;
    }
    __syncthreads();
    if (tid == 0) {
        float4 v;
        v.x = s_red[0][0] + s_red[1][0] + s_red[2][0] + s_red[3][0];
        v.y = s_red[0][1] + s_red[1][1] + s_red[2][1] + s_red[3][1];
        v.z = s_red[0][2] + s_red[1][2] + s_red[2][2] + s_red[3][2];
        v.w = s_red[0][3] + s_red[1][3] + s_red[2][3] + s_red[3][3];
        pblk[bid] = v;
    }
}

// ---- K2: fold the 2112 partials (34KB, L2/L3-hot). Launch boundary = sync. ----
__global__ __launch_bounds__(256)
void yolo_finalize(const float4* __restrict__ pblk, float* __restrict__ out)
{
    __shared__ float s_red[4][12];
    const int tid = threadIdx.x, lane = tid & 63, wave = tid >> 6;

    float v[12];
    #pragma unroll
    for (int j = 0; j < 12; ++j) v[j] = 0.f;
    for (int i = tid; i < NBLK; i += 256) {
        float4 q = pblk[i];
        int k = (i < 1600) ? 0 : (i < 2000) ? 4 : 8;
        v[k + 0] += q.x; v[k + 1] += q.y; v[k + 2] += q.z; v[k + 3] += q.w;
    }
    #pragma unroll
    for (int off = 32; off > 0; off >>= 1) {
        #pragma unroll
        for (int j = 0; j < 12; ++j) v[j] += __shfl_down(v[j], off, 64);
    }
    if (lane == 0) {
        #pragma unroll
        for (int j = 0; j < 12; ++j) s_red[wave][j] = v[j];
    }
    __syncthreads();
    if (tid == 0) {
        float t[12];
        #pragma unroll
        for (int j = 0; j < 12; ++j)
            t[j] = s_red[0][j] + s_red[1][j] + s_red[2][j] + s_red[3][j];
        const float inv_anch[3] = { 1.f / (16.f * 6400.f), 1.f / (16.f * 1600.f), 1.f / (16.f * 400.f) };
        float total = 0.f;
        #pragma unroll
        for (int k = 0; k < 3; ++k) {
            float np = fmaxf(t[k * 4 + 0], 1.f);
            total += 7.5f * t[k * 4 + 1] / np
                   + 0.5f * t[k * 4 + 2] / (np * (float)C_NUM)
                   + t[k * 4 + 3] * inv_anch[k];
        }
        out[0] = total;
    }
}

extern "C" void kernel_launch(void* const* d_in, const int* in_sizes, int n_in,
                              void* d_out, int out_size, void* d_ws, size_t ws_size,
                              hipStream_t stream) {
    const float *cls[3] = {nullptr, nullptr, nullptr};
    const float *reg[3] = {nullptr, nullptr, nullptr};
    const float *tboxes = nullptr;
    const int *t_batch = nullptr, *t_cls = nullptr;
    for (int i = 0; i < n_in; ++i) {
        switch (in_sizes[i]) {
            case 16 * 80 * 6400: cls[0] = (const float*)d_in[i]; break;
            case 16 * 80 * 1600: cls[1] = (const float*)d_in[i]; break;
            case 16 * 80 * 400:  cls[2] = (const float*)d_in[i]; break;
            case 16 * 4 * 6400:  reg[0] = (const float*)d_in[i]; break;
            case 16 * 4 * 1600:  reg[1] = (const float*)d_in[i]; break;
            case 16 * 4 * 400:   reg[2] = (const float*)d_in[i]; break;
            case 256 * 4:        tboxes = (const float*)d_in[i]; break;
            case 256:
                if (!t_batch) t_batch = (const int*)d_in[i];
                else          t_cls   = (const int*)d_in[i];
                break;
            default: break;
        }
    }
    float4* pblk = (float4*)d_ws;       // 2112 float4 partials, all written each call
    float*  out  = (float*)d_out;

    hipLaunchKernelGGL(yolo_main, dim3(NBLK), dim3(256), 0, stream,
                       cls[0], cls[1], cls[2], reg[0], reg[1], reg[2],
                       tboxes, t_batch, t_cls, pblk);
    hipLaunchKernelGGL(yolo_finalize, dim3(1), dim3(256), 0, stream, pblk, out);
}